// Round 4
// baseline (633.858 us; speedup 1.0000x reference)
//
#include <hip/hip_runtime.h>

typedef float f32x4 __attribute__((ext_vector_type(4)));
typedef short s16x8 __attribute__((ext_vector_type(8)));
typedef unsigned int u32;
typedef unsigned long long u64;
typedef unsigned short ush;

#define CD    256
#define NB    64
#define NBETA 512
#define NHID  512
#define PPB   16    // positions per pass_a block
#define NPOS  4096

__device__ __forceinline__ ush f2bf(float x) {
    u32 u = __builtin_bit_cast(u32, x);
    u += 0x7fffu + ((u >> 16) & 1u);
    return (ush)(u >> 16);
}
__device__ __forceinline__ float bf2f(ush h) {
    u32 u = ((u32)h) << 16;
    return __builtin_bit_cast(float, u);
}

// ---------------------------------------------------------------------------
// Prep: htA[beta][b] = h_t[b]·W_h_w[beta] + W_h_b[beta] + W_b[beta] (bf16,
//       stored beta-major for the identity-MFMA A-operand); wwb = bf16(W_w).
// ---------------------------------------------------------------------------
__global__ __launch_bounds__(512) void prep_kernel(
    const float* __restrict__ h_t, const float* __restrict__ W_h_w,
    const float* __restrict__ W_h_b, const float* __restrict__ W_w,
    const float* __restrict__ W_b,
    ush* __restrict__ htA, ush* __restrict__ wwb)
{
    const int blk = blockIdx.x;
    const int tid = threadIdx.x;
    if (blk < NB) {
        __shared__ float hrow[NHID];
        hrow[tid] = h_t[blk * NHID + tid];
        __syncthreads();
        const float* wr = W_h_w + tid * NHID;
        float a0 = 0.f, a1 = 0.f, a2 = 0.f, a3 = 0.f;
        #pragma unroll 4
        for (int h = 0; h < NHID; h += 4) {
            f32x4 wv = *(const f32x4*)(wr + h);
            a0 = fmaf(wv.x, hrow[h], a0);
            a1 = fmaf(wv.y, hrow[h + 1], a1);
            a2 = fmaf(wv.z, hrow[h + 2], a2);
            a3 = fmaf(wv.w, hrow[h + 3], a3);
        }
        float acc = (a0 + a1) + (a2 + a3) + W_h_b[tid] + W_b[tid];
        htA[tid * NB + blk] = f2bf(acc);   // [beta][b]
    } else {
        const int idx = ((blk - NB) * 512 + tid) * 8;
        f32x4 a = *(const f32x4*)(W_w + idx);
        f32x4 b = *(const f32x4*)(W_w + idx + 4);
        s16x8 pk;
        pk[0] = (short)f2bf(a.x); pk[1] = (short)f2bf(a.y);
        pk[2] = (short)f2bf(a.z); pk[3] = (short)f2bf(a.w);
        pk[4] = (short)f2bf(b.x); pk[5] = (short)f2bf(b.y);
        pk[6] = (short)f2bf(b.z); pk[7] = (short)f2bf(b.w);
        *(s16x8*)(wwb + idx) = pk;
    }
}

// ---------------------------------------------------------------------------
// Pass A: per block = (b-half, 16 positions). 8 waves x 64-beta slices.
// U[beta][b] = W_w@V_p (MFMA, K=256) + ht (identity-matrix K-ext, K=32).
// e[b] = sum tanh(U)*bw -> expE[p][b] = exp(e + beta_b). ONE barrier/pos.
// ---------------------------------------------------------------------------
__global__ __launch_bounds__(512, 6) void pass_a(
    const float* __restrict__ V,
    const ush* __restrict__ wwb,
    const ush* __restrict__ htA,
    const float* __restrict__ beta_w,
    const float* __restrict__ beta_b,
    float* __restrict__ expE)
{
    __shared__ __align__(16) char VtB[2][16384];  // [32 b][256 c] bf16 swizzled
    __shared__ float ew[2][8][32];

    const int tid = threadIdx.x;
    const int l = tid & 63, w = tid >> 6, g = l >> 4, r = l & 15;
    const int bh = blockIdx.x & 1;
    const int bl = tid & 31, cg = tid >> 5;

    f32x4 bw[4];
    #pragma unroll
    for (int m = 0; m < 4; ++m)
        bw[m] = *(const f32x4*)(beta_w + w * 64 + m * 16 + g * 4);
    const float bbias = beta_b[0];

    // Identity B-fragments for the hterm K-extension: I[kk][col] = d(kk,col),
    // cols n*16+r, kk = g*8+j  ->  nonzero iff g == (r>>3)+2n at j = r&7.
    s16x8 I0, I1;
    #pragma unroll
    for (int j = 0; j < 8; ++j) {
        I0[j] = (g == (r >> 3)     && j == (r & 7)) ? (short)0x3F80 : (short)0;
        I1[j] = (g == (r >> 3) + 2 && j == (r & 7)) ? (short)0x3F80 : (short)0;
    }

    const int p0 = (blockIdx.x >> 1) * PPB;
    const float* vbase = V + (size_t)p0 * (CD * NB) + bh * 32 + bl;
    const int vswz = (bl & 7) << 4;
    const int xr4 = (r & 7) << 4;
    const ush* wrow = wwb + (w * 64 + r) * CD + g * 8;
    const ush* hrow = htA + (w * 64 + r) * NB + bh * 32 + g * 8;

    // prologue: stage position 0
    {
        float nv[16];
        #pragma unroll
        for (int j = 0; j < 16; ++j)
            nv[j] = __builtin_nontemporal_load(vbase + (cg * 16 + j) * NB);
        char* db = VtB[0] + bl * 512;
        #pragma unroll
        for (int k = 0; k < 2; ++k) {
            s16x8 pk;
            #pragma unroll
            for (int j = 0; j < 8; ++j) pk[j] = (short)f2bf(nv[k * 8 + j]);
            *(s16x8*)(db + ((cg * 32 + k * 16) ^ vswz)) = pk;
        }
    }
    __syncthreads();

    for (int i = 0; i < PPB; ++i) {
        const char* vt = VtB[i & 1];
        const bool pf = (i + 1 < PPB);

        // issue next-position V loads at TOP: covered by MFMA + epilogue
        float nv[16];
        if (pf) {
            const float* vp = vbase + (size_t)(i + 1) * (CD * NB);
            #pragma unroll
            for (int j = 0; j < 16; ++j)
                nv[j] = __builtin_nontemporal_load(vp + (cg * 16 + j) * NB);
        }

        f32x4 acc[4][2];
        #pragma unroll
        for (int m = 0; m < 4; ++m) {
            acc[m][0] = (f32x4){0.f, 0.f, 0.f, 0.f};
            acc[m][1] = (f32x4){0.f, 0.f, 0.f, 0.f};
        }

        // hterm identity block first (its L2 loads issue early)
        #pragma unroll
        for (int m = 0; m < 4; ++m) {
            s16x8 ah = *(const s16x8*)(hrow + m * (16 * NB));
            acc[m][0] = __builtin_amdgcn_mfma_f32_16x16x32_bf16(ah, I0, acc[m][0], 0, 0, 0);
            acc[m][1] = __builtin_amdgcn_mfma_f32_16x16x32_bf16(ah, I1, acc[m][1], 0, 0, 0);
        }

        // U += W_w @ V_p : M=512(beta) N=32(b) K=256(c)
        const char* vrow0 = vt + r * 512;
        #pragma unroll 2
        for (int ks = 0; ks < 8; ++ks) {
            const int off = ((ks << 6) | (g << 4)) ^ xr4;
            s16x8 b0 = *(const s16x8*)(vrow0 + off);
            s16x8 b1 = *(const s16x8*)(vrow0 + 8192 + off);
            #pragma unroll
            for (int m = 0; m < 4; ++m) {
                s16x8 a = *(const s16x8*)(wrow + m * (16 * CD) + ks * 32);
                acc[m][0] = __builtin_amdgcn_mfma_f32_16x16x32_bf16(a, b0, acc[m][0], 0, 0, 0);
                acc[m][1] = __builtin_amdgcn_mfma_f32_16x16x32_bf16(a, b1, acc[m][1], 0, 0, 0);
            }
        }

        // epilogue: pe_n = sum_{m,q} tanh(acc)*bw
        float pe0 = 0.f, pe1 = 0.f;
        #pragma unroll
        for (int m = 0; m < 4; ++m) {
            #pragma unroll
            for (int q = 0; q < 4; ++q) {
                float x0 = acc[m][0][q], x1 = acc[m][1][q];
                float t0 = 1.f - 2.f * __builtin_amdgcn_rcpf(1.f + __expf(x0 + x0));
                float t1 = 1.f - 2.f * __builtin_amdgcn_rcpf(1.f + __expf(x1 + x1));
                pe0 = fmaf(t0, bw[m][q], pe0);
                pe1 = fmaf(t1, bw[m][q], pe1);
            }
        }
        pe0 += __shfl_xor(pe0, 16, 64); pe0 += __shfl_xor(pe0, 32, 64);
        pe1 += __shfl_xor(pe1, 16, 64); pe1 += __shfl_xor(pe1, 32, 64);
        if (l < 16) { ew[i & 1][w][l] = pe0; ew[i & 1][w][16 + l] = pe1; }

        // stage next position (loads have landed under MFMA+epilogue)
        if (pf) {
            char* db = VtB[(i + 1) & 1] + bl * 512;
            #pragma unroll
            for (int k = 0; k < 2; ++k) {
                s16x8 pk;
                #pragma unroll
                for (int j = 0; j < 8; ++j) pk[j] = (short)f2bf(nv[k * 8 + j]);
                *(s16x8*)(db + ((cg * 32 + k * 16) ^ vswz)) = pk;
            }
        }
        __syncthreads();

        if (tid < 32) {
            float e = bbias;
            #pragma unroll
            for (int wv = 0; wv < 8; ++wv) e += ew[i & 1][wv][tid];
            expE[(size_t)(p0 + i) * NB + bh * 32 + tid] = __expf(e);
        }
    }
}

// ---------------------------------------------------------------------------
// Pass B: pure stream. block = (p-chunk of 64, c-quarter of 64).
// num[blk][64c][64b] partial = sum_p expE[p][b] * V[p][c][b]; lsum partial.
// ---------------------------------------------------------------------------
__global__ __launch_bounds__(1024) void pass_b(
    const float* __restrict__ V,
    const float* __restrict__ expE,
    float* __restrict__ num,
    float* __restrict__ lsum)
{
    const int tid = threadIdx.x;
    const int b = tid & 63;
    const int cs = tid >> 6;                 // 16 slices of 4 c
    const int pc = blockIdx.x >> 2;          // 64 position chunks
    const int cq = blockIdx.x & 3;           // 4 c-quarters
    const int c0 = cq * 64 + cs * 4;
    const int p0 = pc * 64;

    float acc0 = 0.f, acc1 = 0.f, acc2 = 0.f, acc3 = 0.f, ls = 0.f;
    for (int p = p0; p < p0 + 64; ++p) {
        float wv = expE[(size_t)p * NB + b];
        ls += wv;
        const float* vp = V + ((size_t)p * CD + c0) * NB + b;
        acc0 = fmaf(wv, __builtin_nontemporal_load(vp),          acc0);
        acc1 = fmaf(wv, __builtin_nontemporal_load(vp + NB),     acc1);
        acc2 = fmaf(wv, __builtin_nontemporal_load(vp + 2 * NB), acc2);
        acc3 = fmaf(wv, __builtin_nontemporal_load(vp + 3 * NB), acc3);
    }
    float* np = num + (size_t)blockIdx.x * (64 * 64) + (size_t)(cs * 4) * 64 + b;
    np[0] = acc0; np[64] = acc1; np[128] = acc2; np[192] = acc3;
    if (cq == 0 && tid < 64) lsum[pc * 64 + tid] = ls;
}

// ---------------------------------------------------------------------------
// Combine: out[b][c] = sum_pc num[pc*4+cq][c&63][b] / sum_pc lsum[pc][b]
// grid = 256 blocks (c), 256 threads (b x 4-way pc split)
// ---------------------------------------------------------------------------
__global__ __launch_bounds__(256) void combine2(
    const float* __restrict__ num, const float* __restrict__ lsum,
    float* __restrict__ out)
{
    __shared__ float rs[4][64];
    __shared__ float rl[4][64];
    const int c = blockIdx.x;
    const int tid = threadIdx.x;
    const int b = tid & 63, kq = tid >> 6;
    const int cq = c >> 6, cl = c & 63;

    float s = 0.f, ls = 0.f;
    #pragma unroll 4
    for (int pc = kq * 16; pc < kq * 16 + 16; ++pc) {
        s += num[(size_t)(pc * 4 + cq) * 4096 + cl * 64 + b];
        ls += lsum[pc * 64 + b];
    }
    rs[kq][b] = s; rl[kq][b] = ls;
    __syncthreads();
    if (kq == 0) {
        float sn = rs[0][b] + rs[1][b] + rs[2][b] + rs[3][b];
        float sl = rl[0][b] + rl[1][b] + rl[2][b] + rl[3][b];
        out[b * CD + c] = sn / sl;
    }
}

extern "C" void kernel_launch(void* const* d_in, const int* in_sizes, int n_in,
                              void* d_out, int out_size, void* d_ws, size_t ws_size,
                              hipStream_t stream)
{
    (void)in_sizes; (void)n_in; (void)out_size; (void)ws_size;
    const float* V      = (const float*)d_in[0];
    const float* h_t    = (const float*)d_in[1];
    const float* W_h_w  = (const float*)d_in[2];
    const float* W_h_b  = (const float*)d_in[3];
    const float* W_w    = (const float*)d_in[4];
    const float* W_b    = (const float*)d_in[5];
    const float* beta_w = (const float*)d_in[6];
    const float* beta_b = (const float*)d_in[7];

    char* ws = (char*)d_ws;
    ush*   wwb  = (ush*)ws;                                  // 256 KB
    ush*   htAp = (ush*)(ws + 262144);                       // 64 KB
    float* expE = (float*)(ws + 262144 + 65536);             // 1 MB
    float* num  = (float*)(ws + 262144 + 65536 + 1048576);   // 4 MB
    float* lsm  = (float*)(ws + 262144 + 65536 + 1048576 + 4194304); // 16 KB

    hipLaunchKernelGGL(prep_kernel, dim3(96), dim3(512), 0, stream,
                       h_t, W_h_w, W_h_b, W_w, W_b, htAp, wwb);
    hipLaunchKernelGGL(pass_a, dim3(512), dim3(512), 0, stream,
                       V, wwb, htAp, beta_w, beta_b, expE);
    hipLaunchKernelGGL(pass_b, dim3(256), dim3(1024), 0, stream,
                       V, expE, num, lsm);
    hipLaunchKernelGGL(combine2, dim3(256), dim3(256), 0, stream,
                       num, lsm, (float*)d_out);
}

// Round 5
// 428.880 us; speedup vs baseline: 1.4779x; 1.4779x over previous
//
#include <hip/hip_runtime.h>

typedef float f32x4 __attribute__((ext_vector_type(4)));
typedef short s16x8 __attribute__((ext_vector_type(8)));
typedef unsigned int u32;
typedef unsigned long long u64;
typedef unsigned short ush;

#define CD    256
#define NB    64
#define NBETA 512
#define NHID  512
#define PPB   16    // positions per pass_a block
#define NPOS  4096

__device__ __forceinline__ ush f2bf(float x) {
    u32 u = __builtin_bit_cast(u32, x);
    u += 0x7fffu + ((u >> 16) & 1u);
    return (ush)(u >> 16);
}
__device__ __forceinline__ float bf2f(ush h) {
    u32 u = ((u32)h) << 16;
    return __builtin_bit_cast(float, u);
}

// ---------------------------------------------------------------------------
// Prep: htA[beta][b] = h_t[b]·W_h_w[beta] + W_h_b[beta] + W_b[beta] (bf16,
//       beta-major for the identity-MFMA A-operand); wwb = bf16(W_w).
// ---------------------------------------------------------------------------
__global__ __launch_bounds__(512) void prep_kernel(
    const float* __restrict__ h_t, const float* __restrict__ W_h_w,
    const float* __restrict__ W_h_b, const float* __restrict__ W_w,
    const float* __restrict__ W_b,
    ush* __restrict__ htA, ush* __restrict__ wwb)
{
    const int blk = blockIdx.x;
    const int tid = threadIdx.x;
    if (blk < NB) {
        __shared__ float hrow[NHID];
        hrow[tid] = h_t[blk * NHID + tid];
        __syncthreads();
        const float* wr = W_h_w + tid * NHID;
        float a0 = 0.f, a1 = 0.f, a2 = 0.f, a3 = 0.f;
        #pragma unroll 4
        for (int h = 0; h < NHID; h += 4) {
            f32x4 wv = *(const f32x4*)(wr + h);
            a0 = fmaf(wv.x, hrow[h], a0);
            a1 = fmaf(wv.y, hrow[h + 1], a1);
            a2 = fmaf(wv.z, hrow[h + 2], a2);
            a3 = fmaf(wv.w, hrow[h + 3], a3);
        }
        float acc = (a0 + a1) + (a2 + a3) + W_h_b[tid] + W_b[tid];
        htA[tid * NB + blk] = f2bf(acc);   // [beta][b]
    } else {
        const int idx = ((blk - NB) * 512 + tid) * 8;
        f32x4 a = *(const f32x4*)(W_w + idx);
        f32x4 b = *(const f32x4*)(W_w + idx + 4);
        s16x8 pk;
        pk[0] = (short)f2bf(a.x); pk[1] = (short)f2bf(a.y);
        pk[2] = (short)f2bf(a.z); pk[3] = (short)f2bf(a.w);
        pk[4] = (short)f2bf(b.x); pk[5] = (short)f2bf(b.y);
        pk[6] = (short)f2bf(b.z); pk[7] = (short)f2bf(b.w);
        *(s16x8*)(wwb + idx) = pk;
    }
}

// ---------------------------------------------------------------------------
// Pass A: block = (b-half, 16 positions), 8 waves x 64-beta slices.
// PAIR-PROCESSED: 2 positions per K-loop so each W_w A-fragment load feeds
// 4 MFMAs; 4-buffer LDS rotation; ONE barrier per 2 positions.
// U = W_w@V_p (K=256) + ht (identity K-ext). expE[p][b] = exp(e + beta_b).
// launch_bounds (512,4): 128-reg budget — acc[4][2][2]=64 must fit (round-4
// lesson: (512,6) => 85-reg budget => 554 MB of scratch spills).
// ---------------------------------------------------------------------------
__global__ __launch_bounds__(512, 4) void pass_a(
    const float* __restrict__ V,
    const ush* __restrict__ wwb,
    const ush* __restrict__ htA,
    const float* __restrict__ beta_w,
    const float* __restrict__ beta_b,
    float* __restrict__ expE)
{
    __shared__ __align__(16) char VtB[4][16384];  // 4 x [32 b][256 c] bf16 swz
    __shared__ float bwS[NBETA];
    __shared__ float ew[2][2][8][32];             // [parity][pos][wave][b]

    const int tid = threadIdx.x;
    const int l = tid & 63, w = tid >> 6, g = l >> 4, r = l & 15;
    const int bh = blockIdx.x & 1;
    const int bl = tid & 31, cg = tid >> 5;

    bwS[tid] = beta_w[tid];
    const float bbias = beta_b[0];

    // Identity B-fragments for hterm K-extension (verified round 4):
    // nonzero iff g == (r>>3)+2n at j = r&7.
    s16x8 I0, I1;
    #pragma unroll
    for (int j = 0; j < 8; ++j) {
        I0[j] = (g == (r >> 3)     && j == (r & 7)) ? (short)0x3F80 : (short)0;
        I1[j] = (g == (r >> 3) + 2 && j == (r & 7)) ? (short)0x3F80 : (short)0;
    }

    const int p0 = (blockIdx.x >> 1) * PPB;
    const float* vbase = V + (size_t)p0 * (CD * NB) + bh * 32 + bl;
    const int vswz = (bl & 7) << 4;
    const int xr4 = (r & 7) << 4;
    const ush* wrow = wwb + (w * 64 + r) * CD + g * 8;
    const ush* hrow = htA + (w * 64 + r) * NB + bh * 32 + g * 8;

    // prologue: stage positions 0,1 into buffers 0,1
    #pragma unroll
    for (int pp = 0; pp < 2; ++pp) {
        float nv[16];
        const float* vp = vbase + (size_t)pp * (CD * NB);
        #pragma unroll
        for (int j = 0; j < 16; ++j)
            nv[j] = __builtin_nontemporal_load(vp + (cg * 16 + j) * NB);
        char* db = VtB[pp] + bl * 512;
        #pragma unroll
        for (int k = 0; k < 2; ++k) {
            s16x8 pk;
            #pragma unroll
            for (int j = 0; j < 8; ++j) pk[j] = (short)f2bf(nv[k * 8 + j]);
            *(s16x8*)(db + ((cg * 32 + k * 16) ^ vswz)) = pk;
        }
    }
    __syncthreads();

    for (int t = 0; t < PPB / 2; ++t) {
        const char* vt0 = VtB[(2 * t) & 3];
        const char* vt1 = VtB[(2 * t + 1) & 3];
        const bool pf = (t + 1 < PPB / 2);

        // (a) issue pos 2t+2 loads — land under the K-loop
        float nv[16];
        if (pf) {
            const float* vp = vbase + (size_t)(2 * t + 2) * (CD * NB);
            #pragma unroll
            for (int j = 0; j < 16; ++j)
                nv[j] = __builtin_nontemporal_load(vp + (cg * 16 + j) * NB);
        }

        f32x4 acc[4][2][2];   // [m][pos][n]
        #pragma unroll
        for (int m = 0; m < 4; ++m)
            #pragma unroll
            for (int pp = 0; pp < 2; ++pp) {
                acc[m][pp][0] = (f32x4){0.f, 0.f, 0.f, 0.f};
                acc[m][pp][1] = (f32x4){0.f, 0.f, 0.f, 0.f};
            }

        // hterm identity block (both positions)
        #pragma unroll
        for (int m = 0; m < 4; ++m) {
            s16x8 ah = *(const s16x8*)(hrow + m * (16 * NB));
            acc[m][0][0] = __builtin_amdgcn_mfma_f32_16x16x32_bf16(ah, I0, acc[m][0][0], 0, 0, 0);
            acc[m][0][1] = __builtin_amdgcn_mfma_f32_16x16x32_bf16(ah, I1, acc[m][0][1], 0, 0, 0);
            acc[m][1][0] = __builtin_amdgcn_mfma_f32_16x16x32_bf16(ah, I0, acc[m][1][0], 0, 0, 0);
            acc[m][1][1] = __builtin_amdgcn_mfma_f32_16x16x32_bf16(ah, I1, acc[m][1][1], 0, 0, 0);
        }

        // K-loop: each a-fragment feeds 4 MFMAs (2 pos x 2 n)
        const char* vr0 = vt0 + r * 512;
        const char* vr1 = vt1 + r * 512;
        #pragma unroll 2
        for (int ks = 0; ks < 8; ++ks) {
            const int off = ((ks << 6) | (g << 4)) ^ xr4;
            s16x8 b00 = *(const s16x8*)(vr0 + off);
            s16x8 b01 = *(const s16x8*)(vr0 + 8192 + off);
            s16x8 b10 = *(const s16x8*)(vr1 + off);
            s16x8 b11 = *(const s16x8*)(vr1 + 8192 + off);
            #pragma unroll
            for (int m = 0; m < 4; ++m) {
                s16x8 a = *(const s16x8*)(wrow + m * (16 * CD) + ks * 32);
                acc[m][0][0] = __builtin_amdgcn_mfma_f32_16x16x32_bf16(a, b00, acc[m][0][0], 0, 0, 0);
                acc[m][0][1] = __builtin_amdgcn_mfma_f32_16x16x32_bf16(a, b01, acc[m][0][1], 0, 0, 0);
                acc[m][1][0] = __builtin_amdgcn_mfma_f32_16x16x32_bf16(a, b10, acc[m][1][0], 0, 0, 0);
                acc[m][1][1] = __builtin_amdgcn_mfma_f32_16x16x32_bf16(a, b11, acc[m][1][1], 0, 0, 0);
            }
        }

        // (d) stage pos 2t+2
        if (pf) {
            char* db = VtB[(2 * t + 2) & 3] + bl * 512;
            #pragma unroll
            for (int k = 0; k < 2; ++k) {
                s16x8 pk;
                #pragma unroll
                for (int j = 0; j < 8; ++j) pk[j] = (short)f2bf(nv[k * 8 + j]);
                *(s16x8*)(db + ((cg * 32 + k * 16) ^ vswz)) = pk;
            }
        }
        // (e) issue pos 2t+3 loads — land under the tanh epilogue
        if (pf) {
            const float* vp = vbase + (size_t)(2 * t + 3) * (CD * NB);
            #pragma unroll
            for (int j = 0; j < 16; ++j)
                nv[j] = __builtin_nontemporal_load(vp + (cg * 16 + j) * NB);
        }

        // (f) epilogue: pe[pos][n] = sum_{m,q} tanh(acc)*bw
        float pe00 = 0.f, pe01 = 0.f, pe10 = 0.f, pe11 = 0.f;
        #pragma unroll
        for (int m = 0; m < 4; ++m) {
            f32x4 bwv = *(const f32x4*)(&bwS[w * 64 + m * 16 + g * 4]);
            #pragma unroll
            for (int q = 0; q < 4; ++q) {
                float x00 = acc[m][0][0][q], x01 = acc[m][0][1][q];
                float x10 = acc[m][1][0][q], x11 = acc[m][1][1][q];
                float t00 = 1.f - 2.f * __builtin_amdgcn_rcpf(1.f + __expf(x00 + x00));
                float t01 = 1.f - 2.f * __builtin_amdgcn_rcpf(1.f + __expf(x01 + x01));
                float t10 = 1.f - 2.f * __builtin_amdgcn_rcpf(1.f + __expf(x10 + x10));
                float t11 = 1.f - 2.f * __builtin_amdgcn_rcpf(1.f + __expf(x11 + x11));
                pe00 = fmaf(t00, bwv[q], pe00);
                pe01 = fmaf(t01, bwv[q], pe01);
                pe10 = fmaf(t10, bwv[q], pe10);
                pe11 = fmaf(t11, bwv[q], pe11);
            }
        }
        pe00 += __shfl_xor(pe00, 16, 64); pe00 += __shfl_xor(pe00, 32, 64);
        pe01 += __shfl_xor(pe01, 16, 64); pe01 += __shfl_xor(pe01, 32, 64);
        pe10 += __shfl_xor(pe10, 16, 64); pe10 += __shfl_xor(pe10, 32, 64);
        pe11 += __shfl_xor(pe11, 16, 64); pe11 += __shfl_xor(pe11, 32, 64);
        if (l < 16) {
            ew[t & 1][0][w][l]      = pe00;
            ew[t & 1][0][w][16 + l] = pe01;
            ew[t & 1][1][w][l]      = pe10;
            ew[t & 1][1][w][16 + l] = pe11;
        }

        // (g) stage pos 2t+3
        if (pf) {
            char* db = VtB[(2 * t + 3) & 3] + bl * 512;
            #pragma unroll
            for (int k = 0; k < 2; ++k) {
                s16x8 pk;
                #pragma unroll
                for (int j = 0; j < 8; ++j) pk[j] = (short)f2bf(nv[k * 8 + j]);
                *(s16x8*)(db + ((cg * 32 + k * 16) ^ vswz)) = pk;
            }
        }
        __syncthreads();   // the ONLY barrier per pair

        // (i) expE for both positions of the pair
        if (tid < 64) {
            const int pp = tid >> 5, bb = tid & 31;
            float e = bbias;
            #pragma unroll
            for (int wv = 0; wv < 8; ++wv) e += ew[t & 1][pp][wv][bb];
            expE[(size_t)(p0 + 2 * t + pp) * NB + bh * 32 + bb] = __expf(e);
        }
    }
}

// ---------------------------------------------------------------------------
// Pass B: pure stream. block = (p-chunk of 64, c-quarter of 64).
// ---------------------------------------------------------------------------
__global__ __launch_bounds__(1024) void pass_b(
    const float* __restrict__ V,
    const float* __restrict__ expE,
    float* __restrict__ num,
    float* __restrict__ lsum)
{
    const int tid = threadIdx.x;
    const int b = tid & 63;
    const int cs = tid >> 6;
    const int pc = blockIdx.x >> 2;
    const int cq = blockIdx.x & 3;
    const int c0 = cq * 64 + cs * 4;
    const int p0 = pc * 64;

    float acc0 = 0.f, acc1 = 0.f, acc2 = 0.f, acc3 = 0.f, ls = 0.f;
    for (int p = p0; p < p0 + 64; ++p) {
        float wv = expE[(size_t)p * NB + b];
        ls += wv;
        const float* vp = V + ((size_t)p * CD + c0) * NB + b;
        acc0 = fmaf(wv, __builtin_nontemporal_load(vp),          acc0);
        acc1 = fmaf(wv, __builtin_nontemporal_load(vp + NB),     acc1);
        acc2 = fmaf(wv, __builtin_nontemporal_load(vp + 2 * NB), acc2);
        acc3 = fmaf(wv, __builtin_nontemporal_load(vp + 3 * NB), acc3);
    }
    float* np = num + (size_t)blockIdx.x * (64 * 64) + (size_t)(cs * 4) * 64 + b;
    np[0] = acc0; np[64] = acc1; np[128] = acc2; np[192] = acc3;
    if (cq == 0 && tid < 64) lsum[pc * 64 + tid] = ls;
}

// ---------------------------------------------------------------------------
// Combine: out[b][c] = sum_pc num[pc*4+cq][c&63][b] / sum_pc lsum[pc][b]
// ---------------------------------------------------------------------------
__global__ __launch_bounds__(256) void combine2(
    const float* __restrict__ num, const float* __restrict__ lsum,
    float* __restrict__ out)
{
    __shared__ float rs[4][64];
    __shared__ float rl[4][64];
    const int c = blockIdx.x;
    const int tid = threadIdx.x;
    const int b = tid & 63, kq = tid >> 6;
    const int cq = c >> 6, cl = c & 63;

    float s = 0.f, ls = 0.f;
    #pragma unroll 4
    for (int pc = kq * 16; pc < kq * 16 + 16; ++pc) {
        s += num[(size_t)(pc * 4 + cq) * 4096 + cl * 64 + b];
        ls += lsum[pc * 64 + b];
    }
    rs[kq][b] = s; rl[kq][b] = ls;
    __syncthreads();
    if (kq == 0) {
        float sn = rs[0][b] + rs[1][b] + rs[2][b] + rs[3][b];
        float sl = rl[0][b] + rl[1][b] + rl[2][b] + rl[3][b];
        out[b * CD + c] = sn / sl;
    }
}

extern "C" void kernel_launch(void* const* d_in, const int* in_sizes, int n_in,
                              void* d_out, int out_size, void* d_ws, size_t ws_size,
                              hipStream_t stream)
{
    (void)in_sizes; (void)n_in; (void)out_size; (void)ws_size;
    const float* V      = (const float*)d_in[0];
    const float* h_t    = (const float*)d_in[1];
    const float* W_h_w  = (const float*)d_in[2];
    const float* W_h_b  = (const float*)d_in[3];
    const float* W_w    = (const float*)d_in[4];
    const float* W_b    = (const float*)d_in[5];
    const float* beta_w = (const float*)d_in[6];
    const float* beta_b = (const float*)d_in[7];

    char* ws = (char*)d_ws;
    ush*   wwb  = (ush*)ws;                                  // 256 KB
    ush*   htAp = (ush*)(ws + 262144);                       // 64 KB
    float* expE = (float*)(ws + 262144 + 65536);             // 1 MB
    float* num  = (float*)(ws + 262144 + 65536 + 1048576);   // 4 MB
    float* lsm  = (float*)(ws + 262144 + 65536 + 1048576 + 4194304); // 16 KB

    hipLaunchKernelGGL(prep_kernel, dim3(96), dim3(512), 0, stream,
                       h_t, W_h_w, W_h_b, W_w, W_b, htAp, wwb);
    hipLaunchKernelGGL(pass_a, dim3(512), dim3(512), 0, stream,
                       V, wwb, htAp, beta_w, beta_b, expE);
    hipLaunchKernelGGL(pass_b, dim3(256), dim3(1024), 0, stream,
                       V, expE, num, lsm);
    hipLaunchKernelGGL(combine2, dim3(256), dim3(256), 0, stream,
                       num, lsm, (float*)d_out);
}

// Round 6
// 178.268 us; speedup vs baseline: 3.5557x; 2.4058x over previous
//
#include <hip/hip_runtime.h>

typedef float f32x4 __attribute__((ext_vector_type(4)));
typedef short s16x8 __attribute__((ext_vector_type(8)));
typedef unsigned int u32;
typedef unsigned long long u64;
typedef unsigned short ush;

#define CD    256
#define NB    64
#define NBETA 512
#define NHID  512
#define PPB   32    // positions per pass_a block

__device__ __forceinline__ ush f2bf(float x) {
    u32 u = __builtin_bit_cast(u32, x);
    u += 0x7fffu + ((u >> 16) & 1u);
    return (ush)(u >> 16);
}
__device__ __forceinline__ float bf2f(ush h) {
    u32 u = ((u32)h) << 16;
    return __builtin_bit_cast(float, u);
}

// ---------------------------------------------------------------------------
// Prep: hws[b][beta] = h_t[b]·W_h_w[beta] + W_h_b[beta] + W_b[beta] (bf16,
//       b-major so per-lane u64 grabs 4 consecutive betas); wwb = bf16(W_w).
// ---------------------------------------------------------------------------
__global__ __launch_bounds__(512) void prep_kernel(
    const float* __restrict__ h_t, const float* __restrict__ W_h_w,
    const float* __restrict__ W_h_b, const float* __restrict__ W_w,
    const float* __restrict__ W_b,
    ush* __restrict__ hws, ush* __restrict__ wwb)
{
    const int blk = blockIdx.x;
    const int tid = threadIdx.x;
    if (blk < NB) {
        __shared__ float hrow[NHID];
        hrow[tid] = h_t[blk * NHID + tid];
        __syncthreads();
        const float* wr = W_h_w + tid * NHID;
        float a0 = 0.f, a1 = 0.f, a2 = 0.f, a3 = 0.f;
        #pragma unroll 4
        for (int h = 0; h < NHID; h += 4) {
            f32x4 wv = *(const f32x4*)(wr + h);
            a0 = fmaf(wv.x, hrow[h], a0);
            a1 = fmaf(wv.y, hrow[h + 1], a1);
            a2 = fmaf(wv.z, hrow[h + 2], a2);
            a3 = fmaf(wv.w, hrow[h + 3], a3);
        }
        float acc = (a0 + a1) + (a2 + a3) + W_h_b[tid] + W_b[tid];
        hws[blk * NBETA + tid] = f2bf(acc);   // [b][beta]
    } else {
        const int idx = ((blk - NB) * 512 + tid) * 8;
        f32x4 a = *(const f32x4*)(W_w + idx);
        f32x4 b = *(const f32x4*)(W_w + idx + 4);
        s16x8 pk;
        pk[0] = (short)f2bf(a.x); pk[1] = (short)f2bf(a.y);
        pk[2] = (short)f2bf(a.z); pk[3] = (short)f2bf(a.w);
        pk[4] = (short)f2bf(b.x); pk[5] = (short)f2bf(b.y);
        pk[6] = (short)f2bf(b.z); pk[7] = (short)f2bf(b.w);
        *(s16x8*)(wwb + idx) = pk;
    }
}

// ---------------------------------------------------------------------------
// Pass A: block = (chunk of 32 pos, beta-half, b-half); 8 waves x 32 betas.
// W_w A-fragments live in REGISTERS for the whole block (64 VGPR/lane) ->
// K-loop is pure LDS+MFMA, no L2 re-reads (round-3/5 stall source).
// hterm: position-invariant per-lane u64 x4 preload, unpacked as acc-init.
// Emits PARTIAL e (this block's 256 betas); ecomb sums halves + exp.
// ---------------------------------------------------------------------------
__global__ __launch_bounds__(512, 4) void pass_a(
    const float* __restrict__ V,
    const ush* __restrict__ wwb,
    const ush* __restrict__ hws,
    const float* __restrict__ beta_w,
    float* __restrict__ eP)
{
    __shared__ __align__(16) char VtB[2][16384];  // [32 b][256 c] bf16 swizzled
    __shared__ float bwS[256];
    __shared__ float ew[2][8][32];

    const int tid = threadIdx.x;
    const int l = tid & 63, w = tid >> 6, g = l >> 4, r = l & 15;
    const int bl = tid & 31, cg = tid >> 5;

    // XCD-chunked work id: hw block b -> xcd b%8; work (b%8)*64 + b/8 keeps
    // the 4 sibling blocks of a chunk (betah x bh) on one XCD's L2.
    const int w0 = (blockIdx.x & 7) * 64 + (blockIdx.x >> 3);
    const int chunk = w0 >> 2, betah = (w0 >> 1) & 1, bh = w0 & 1;

    if (tid < 256) bwS[tid] = beta_w[betah * 256 + tid];

    // permanent A fragments: a[m][ks], beta = betah*256 + w*32 + m*16 + r
    const ush* wbase = wwb + (size_t)(betah * 256 + w * 32 + r) * CD + g * 8;
    s16x8 a[2][8];
    #pragma unroll
    for (int m = 0; m < 2; ++m)
        #pragma unroll
        for (int ks = 0; ks < 8; ++ks)
            a[m][ks] = *(const s16x8*)(wbase + m * (16 * CD) + ks * 32);

    // permanent hterm: ua[m][n] = 4 betas (q) at b = bh*32 + n*16 + r
    const ush* hbase = hws + (size_t)(bh * 32 + r) * NBETA
                     + betah * 256 + w * 32 + g * 4;
    u64 ua[2][2];
    #pragma unroll
    for (int m = 0; m < 2; ++m)
        #pragma unroll
        for (int n = 0; n < 2; ++n)
            ua[m][n] = *(const u64*)(hbase + n * (16 * NBETA) + m * 16);

    const int p0 = chunk * PPB;
    const float* vbase = V + (size_t)p0 * (CD * NB) + bh * 32 + bl;
    const int vswz = (bl & 7) << 4;
    const int xr4 = (r & 7) << 4;

    // prologue: stage position 0
    {
        float nv[16];
        #pragma unroll
        for (int j = 0; j < 16; ++j)
            nv[j] = vbase[(cg * 16 + j) * NB];
        char* db = VtB[0] + bl * 512;
        #pragma unroll
        for (int k = 0; k < 2; ++k) {
            s16x8 pk;
            #pragma unroll
            for (int j = 0; j < 8; ++j) pk[j] = (short)f2bf(nv[k * 8 + j]);
            *(s16x8*)(db + ((cg * 32 + k * 16) ^ vswz)) = pk;
        }
    }
    __syncthreads();

    for (int i = 0; i < PPB; ++i) {
        const char* vt = VtB[i & 1];
        const bool pf = (i + 1 < PPB);

        // issue next-position loads; they land under the K-loop + epilogue
        float nv[16];
        if (pf) {
            const float* vp = vbase + (size_t)(i + 1) * (CD * NB);
            #pragma unroll
            for (int j = 0; j < 16; ++j)
                nv[j] = vp[(cg * 16 + j) * NB];
        }

        // acc init = hterm (position-invariant registers)
        f32x4 acc[2][2];
        #pragma unroll
        for (int m = 0; m < 2; ++m)
            #pragma unroll
            for (int n = 0; n < 2; ++n) {
                u64 h = ua[m][n];
                acc[m][n] = (f32x4){bf2f((ush)h), bf2f((ush)(h >> 16)),
                                    bf2f((ush)(h >> 32)), bf2f((ush)(h >> 48))};
            }

        // K-loop: pure LDS + MFMA (A in regs)
        const char* vrow0 = vt + r * 512;
        #pragma unroll
        for (int ks = 0; ks < 8; ++ks) {
            const int off = ((ks << 6) | (g << 4)) ^ xr4;
            s16x8 b0 = *(const s16x8*)(vrow0 + off);
            s16x8 b1 = *(const s16x8*)(vrow0 + 8192 + off);
            #pragma unroll
            for (int m = 0; m < 2; ++m) {
                acc[m][0] = __builtin_amdgcn_mfma_f32_16x16x32_bf16(a[m][ks], b0, acc[m][0], 0, 0, 0);
                acc[m][1] = __builtin_amdgcn_mfma_f32_16x16x32_bf16(a[m][ks], b1, acc[m][1], 0, 0, 0);
            }
        }

        // epilogue: pe_n = sum_{m,q} tanh(acc)*bw
        float pe0 = 0.f, pe1 = 0.f;
        #pragma unroll
        for (int m = 0; m < 2; ++m) {
            f32x4 bwv = *(const f32x4*)(&bwS[w * 32 + m * 16 + g * 4]);
            #pragma unroll
            for (int q = 0; q < 4; ++q) {
                float x0 = acc[m][0][q], x1 = acc[m][1][q];
                float t0 = 1.f - 2.f * __builtin_amdgcn_rcpf(1.f + __expf(x0 + x0));
                float t1 = 1.f - 2.f * __builtin_amdgcn_rcpf(1.f + __expf(x1 + x1));
                pe0 = fmaf(t0, bwv[q], pe0);
                pe1 = fmaf(t1, bwv[q], pe1);
            }
        }
        pe0 += __shfl_xor(pe0, 16, 64); pe0 += __shfl_xor(pe0, 32, 64);
        pe1 += __shfl_xor(pe1, 16, 64); pe1 += __shfl_xor(pe1, 32, 64);
        if (l < 16) { ew[i & 1][w][l] = pe0; ew[i & 1][w][16 + l] = pe1; }

        // stage next position
        if (pf) {
            char* db = VtB[(i + 1) & 1] + bl * 512;
            #pragma unroll
            for (int k = 0; k < 2; ++k) {
                s16x8 pk;
                #pragma unroll
                for (int j = 0; j < 8; ++j) pk[j] = (short)f2bf(nv[k * 8 + j]);
                *(s16x8*)(db + ((cg * 32 + k * 16) ^ vswz)) = pk;
            }
        }
        __syncthreads();

        // partial e over this block's 256 betas
        if (tid < 32) {
            float e = 0.f;
            #pragma unroll
            for (int wv = 0; wv < 8; ++wv) e += ew[i & 1][wv][tid];
            eP[(size_t)(p0 + i) * 128 + betah * 64 + bh * 32 + tid] = e;
        }
    }
}

// ---------------------------------------------------------------------------
// ecomb: expE[p][b] = exp(beta_b + eP[p][0][b] + eP[p][1][b])
// ---------------------------------------------------------------------------
__global__ __launch_bounds__(1024) void ecomb(
    const float* __restrict__ eP, const float* __restrict__ beta_b,
    float* __restrict__ expE)
{
    const int i = blockIdx.x * 1024 + threadIdx.x;   // 4096*64
    const int p = i >> 6, b = i & 63;
    expE[i] = __expf(beta_b[0] + eP[p * 128 + b] + eP[p * 128 + 64 + b]);
}

// ---------------------------------------------------------------------------
// Pass B: pure stream. block = (p-chunk of 64, c-quarter of 64).
// ---------------------------------------------------------------------------
__global__ __launch_bounds__(1024) void pass_b(
    const float* __restrict__ V,
    const float* __restrict__ expE,
    float* __restrict__ num,
    float* __restrict__ lsum)
{
    const int tid = threadIdx.x;
    const int b = tid & 63;
    const int cs = tid >> 6;
    const int pc = blockIdx.x >> 2;
    const int cq = blockIdx.x & 3;
    const int c0 = cq * 64 + cs * 4;
    const int p0 = pc * 64;

    float acc0 = 0.f, acc1 = 0.f, acc2 = 0.f, acc3 = 0.f, ls = 0.f;
    for (int p = p0; p < p0 + 64; ++p) {
        float wv = expE[(size_t)p * NB + b];
        ls += wv;
        const float* vp = V + ((size_t)p * CD + c0) * NB + b;
        acc0 = fmaf(wv, __builtin_nontemporal_load(vp),          acc0);
        acc1 = fmaf(wv, __builtin_nontemporal_load(vp + NB),     acc1);
        acc2 = fmaf(wv, __builtin_nontemporal_load(vp + 2 * NB), acc2);
        acc3 = fmaf(wv, __builtin_nontemporal_load(vp + 3 * NB), acc3);
    }
    float* np = num + (size_t)blockIdx.x * (64 * 64) + (size_t)(cs * 4) * 64 + b;
    np[0] = acc0; np[64] = acc1; np[128] = acc2; np[192] = acc3;
    if (cq == 0 && tid < 64) lsum[pc * 64 + tid] = ls;
}

// ---------------------------------------------------------------------------
// Combine: out[b][c] = sum_pc num[pc*4+cq][c&63][b] / sum_pc lsum[pc][b]
// ---------------------------------------------------------------------------
__global__ __launch_bounds__(256) void combine2(
    const float* __restrict__ num, const float* __restrict__ lsum,
    float* __restrict__ out)
{
    __shared__ float rs[4][64];
    __shared__ float rl[4][64];
    const int c = blockIdx.x;
    const int tid = threadIdx.x;
    const int b = tid & 63, kq = tid >> 6;
    const int cq = c >> 6, cl = c & 63;

    float s = 0.f, ls = 0.f;
    #pragma unroll 4
    for (int pc = kq * 16; pc < kq * 16 + 16; ++pc) {
        s += num[(size_t)(pc * 4 + cq) * 4096 + cl * 64 + b];
        ls += lsum[pc * 64 + b];
    }
    rs[kq][b] = s; rl[kq][b] = ls;
    __syncthreads();
    if (kq == 0) {
        float sn = rs[0][b] + rs[1][b] + rs[2][b] + rs[3][b];
        float sl = rl[0][b] + rl[1][b] + rl[2][b] + rl[3][b];
        out[b * CD + c] = sn / sl;
    }
}

extern "C" void kernel_launch(void* const* d_in, const int* in_sizes, int n_in,
                              void* d_out, int out_size, void* d_ws, size_t ws_size,
                              hipStream_t stream)
{
    (void)in_sizes; (void)n_in; (void)out_size; (void)ws_size;
    const float* V      = (const float*)d_in[0];
    const float* h_t    = (const float*)d_in[1];
    const float* W_h_w  = (const float*)d_in[2];
    const float* W_h_b  = (const float*)d_in[3];
    const float* W_w    = (const float*)d_in[4];
    const float* W_b    = (const float*)d_in[5];
    const float* beta_w = (const float*)d_in[6];
    const float* beta_b = (const float*)d_in[7];

    char* ws = (char*)d_ws;
    ush*   wwb  = (ush*)ws;                                   // 256 KB
    ush*   hws  = (ush*)(ws + 262144);                        // 64 KB
    float* eP   = (float*)(ws + 262144 + 65536);              // 2 MB
    float* expE = (float*)(ws + 262144 + 65536 + 2097152);    // 1 MB
    float* num  = (float*)(ws + 262144 + 65536 + 2097152 + 1048576);  // 4 MB
    float* lsm  = (float*)(ws + 262144 + 65536 + 2097152 + 1048576 + 4194304);

    hipLaunchKernelGGL(prep_kernel, dim3(96), dim3(512), 0, stream,
                       h_t, W_h_w, W_h_b, W_w, W_b, hws, wwb);
    hipLaunchKernelGGL(pass_a, dim3(512), dim3(512), 0, stream,
                       V, wwb, hws, beta_w, eP);
    hipLaunchKernelGGL(ecomb, dim3(256), dim3(1024), 0, stream,
                       eP, beta_b, expE);
    hipLaunchKernelGGL(pass_b, dim3(256), dim3(1024), 0, stream,
                       V, expE, num, lsm);
    hipLaunchKernelGGL(combine2, dim3(256), dim3(256), 0, stream,
                       num, lsm, (float*)d_out);
}